// Round 4
// baseline (67.757 us; speedup 1.0000x reference)
//
#include <hip/hip_runtime.h>
#include <hip/hip_bf16.h>

typedef __bf16 bf16x8 __attribute__((ext_vector_type(8)));
typedef __bf16 bf16x4 __attribute__((ext_vector_type(4)));
typedef float  f32x4  __attribute__((ext_vector_type(4)));
typedef unsigned short u16;

#define NPROT 8192
#define NLIG  2048
#define DMODEL 128
#define NHEAD 8
#define NBATCH 32
#define PPB 256
#define LPB 64
#define TR 32

__device__ __forceinline__ u16 f2bf(float f){
  union { float f; unsigned int u; } v; v.f = f;
  return (u16)((v.u + 0x7FFFu + ((v.u >> 16) & 1u)) >> 16);
}

__device__ __forceinline__ bf16x8 cvt8(const float* p){
  float4 a = *(const float4*)p, b = *(const float4*)(p + 4);
  bf16x8 r;
  r[0]=(__bf16)a.x; r[1]=(__bf16)a.y; r[2]=(__bf16)a.z; r[3]=(__bf16)a.w;
  r[4]=(__bf16)b.x; r[5]=(__bf16)b.y; r[6]=(__bf16)b.z; r[7]=(__bf16)b.w;
  return r;
}

// ================= L1: qkv GEMM (self-transposing W) + prep transpose blocks =================
struct QkvJob { const float* A; const float* Wsrc[3]; u16* outB; int blockStart; };
struct TJob { const float* src; u16* dst; int M, K, tilesX, blockStart; };
struct L1Args {
  QkvJob qjobs[2];
  int nQkv;
  int nprep;
  TJob pjobs[10];
};

__global__ __launch_bounds__(256) void l1_kernel(L1Args a){
  __shared__ u16 Wl[64][136];      // qkv branch: transposed weight tile
  __shared__ float tile[32][33];   // prep branch
  int bid = (int)blockIdx.x;
  int tid = (int)threadIdx.x;
  if (bid < a.nQkv){
    int j = (bid >= a.qjobs[1].blockStart) ? 1 : 0;
    const QkvJob jb = a.qjobs[j];
    int t = bid - jb.blockStart;
    int tn = t / 6, tm = t - tn * 6;
    // ---- stage W[128][64-col tile] -> Wl[col][k] bf16 ----
    {
      int midx = tm >> 1;
      int cb64 = (tm & 1) * 64;
      const float* Ws = jb.Wsrc[midx];
      int kr = tid >> 2;
      int cb = (tid & 3) * 16;
      #pragma unroll
      for (int p = 0; p < 2; ++p){
        int k = p * 64 + kr;
        const float* srcp = Ws + (size_t)k * 128 + cb64 + cb;
        float4 v0 = *(const float4*)srcp,     v1 = *(const float4*)(srcp + 4);
        float4 v2 = *(const float4*)(srcp+8), v3 = *(const float4*)(srcp + 12);
        float tmp[16] = {v0.x,v0.y,v0.z,v0.w, v1.x,v1.y,v1.z,v1.w,
                         v2.x,v2.y,v2.z,v2.w, v3.x,v3.y,v3.z,v3.w};
        #pragma unroll
        for (int i = 0; i < 16; ++i) Wl[cb + i][k] = f2bf(tmp[i]);
      }
    }
    __syncthreads();
    int w = tid >> 6, l = tid & 63;
    int roff = tn * 64 + (w >> 1) * 32;
    int cloc = (w & 1) * 32;
    int lr = l & 15, lk = (l >> 4) * 8;
    f32x4 a00 = {0.f,0.f,0.f,0.f}, a01 = a00, a10 = a00, a11 = a00;
    const float* Af  = jb.A + (size_t)(roff + lr) * 128 + lk;
    const float* Af2 = Af + 16 * 128;
    #pragma unroll
    for (int kk = 0; kk < 128; kk += 32){
      bf16x8 a0 = cvt8(Af + kk);
      bf16x8 a1 = cvt8(Af2 + kk);
      bf16x8 b0 = *(const bf16x8*)&Wl[cloc + lr][kk + lk];
      bf16x8 b1 = *(const bf16x8*)&Wl[cloc + 16 + lr][kk + lk];
      a00 = __builtin_amdgcn_mfma_f32_16x16x32_bf16(a0, b0, a00, 0, 0, 0);
      a01 = __builtin_amdgcn_mfma_f32_16x16x32_bf16(a0, b1, a01, 0, 0, 0);
      a10 = __builtin_amdgcn_mfma_f32_16x16x32_bf16(a1, b0, a10, 0, 0, 0);
      a11 = __builtin_amdgcn_mfma_f32_16x16x32_bf16(a1, b1, a11, 0, 0, 0);
    }
    int rbase = roff + ((l >> 4) << 2);
    f32x4 av[2][2] = {{a00, a01}, {a10, a11}};
    #pragma unroll
    for (int i = 0; i < 2; ++i)
      #pragma unroll
      for (int jj = 0; jj < 2; ++jj)
        #pragma unroll
        for (int e = 0; e < 4; ++e){
          int rr = rbase + i * 16 + e;
          int cc = tm * 64 + cloc + jj * 16 + lr;
          jb.outB[(size_t)rr * 384 + cc] = f2bf(av[i][jj][e]);
        }
  } else {
    int pb = bid - a.nQkv;
    int j = 0;
    while (j + 1 < a.nprep && pb >= a.pjobs[j + 1].blockStart) ++j;
    const TJob jb = a.pjobs[j];
    int t = pb - jb.blockStart;
    int tm = t % jb.tilesX, tk = t / jb.tilesX;
    int c = tid & 31, r0 = tid >> 5;
    #pragma unroll
    for (int p = 0; p < 4; ++p)
      tile[r0 + p * 8][c] = jb.src[(size_t)(tk * 32 + r0 + p * 8) * jb.M + tm * 32 + c];
    __syncthreads();
    #pragma unroll
    for (int p = 0; p < 4; ++p)
      jb.dst[(size_t)(tm * 32 + r0 + p * 8) * jb.K + tk * 32 + c] = f2bf(tile[c][r0 + p * 8]);
  }
}

// ================= L2: attention, one direction per block (512 blocks) =================
__global__ __launch_bounds__(256) void attn_kernel(
    const u16* __restrict__ qkv_p, const u16* __restrict__ qkv_l,
    u16* __restrict__ ctx_p, u16* __restrict__ ctx_l)
{
  __shared__ u16 P_s[256 * 72];    // prot: [256][72]; lig view: [64][264]
  __shared__ u16 vT_s[16 * 264];   // lig: [16][264]; prot view: [16][72]
  __shared__ float cpart[4][64][17];
  __shared__ float redA[4][4][16];
  __shared__ float redB[4][4][16];
  __shared__ float den[256];

  int bid = (int)blockIdx.x;
  int tid = (int)threadIdx.x, w = tid >> 6, l = tid & 63;
  int lr = l & 15, lg = l >> 4;

  bf16x8 zero8;
  #pragma unroll
  for (int i = 0; i < 8; ++i) zero8[i] = (__bf16)0.f;

  if (bid < NBATCH * NHEAD){
    // ---- ligand queries (64) over protein keys (256) ----
    int b = bid >> 3, h = bid & 7;
    const u16* qp = qkv_p + (size_t)b * PPB * 384;
    const u16* ql = qkv_l + (size_t)b * LPB * 384;
    {
      const u16* src = qp + (size_t)tid * 384 + 256 + h * 16;
      bf16x8 v0 = *(const bf16x8*)src;
      bf16x8 v1 = *(const bf16x8*)(src + 8);
      #pragma unroll
      for (int i = 0; i < 8; ++i){
        vT_s[i * 264 + tid]       = ((const u16*)&v0)[i];
        vT_s[(i + 8) * 264 + tid] = ((const u16*)&v1)[i];
      }
    }
    f32x4 acc[4][4];
    #pragma unroll
    for (int kt = 0; kt < 4; ++kt)
      #pragma unroll
      for (int qt = 0; qt < 4; ++qt) acc[kt][qt] = (f32x4){0.f,0.f,0.f,0.f};
    {
      bf16x8 afr[4], bfr[4];
      #pragma unroll
      for (int kt = 0; kt < 4; ++kt)
        afr[kt] = (l < 32) ? *(const bf16x8*)(qp + (size_t)(w * 64 + kt * 16 + lr) * 384 + 128 + h * 16 + lg * 8) : zero8;
      #pragma unroll
      for (int qt = 0; qt < 4; ++qt)
        bfr[qt] = (l < 32) ? *(const bf16x8*)(ql + (size_t)(qt * 16 + lr) * 384 + h * 16 + lg * 8) : zero8;
      #pragma unroll
      for (int kt = 0; kt < 4; ++kt)
        #pragma unroll
        for (int qt = 0; qt < 4; ++qt)
          acc[kt][qt] = __builtin_amdgcn_mfma_f32_16x16x32_bf16(afr[kt], bfr[qt], acc[kt][qt], 0, 0, 0);
    }
    #pragma unroll
    for (int qt = 0; qt < 4; ++qt){
      float m = -1e30f;
      #pragma unroll
      for (int kt = 0; kt < 4; ++kt)
        #pragma unroll
        for (int e = 0; e < 4; ++e) m = fmaxf(m, acc[kt][qt][e]);
      m = fmaxf(m, __shfl_xor(m, 16)); m = fmaxf(m, __shfl_xor(m, 32));
      if (l < 16) redA[w][qt][lr] = m;
    }
    __syncthreads();  // #1
    float gm[4];
    #pragma unroll
    for (int qt = 0; qt < 4; ++qt)
      gm[qt] = fmaxf(fmaxf(redA[0][qt][lr], redA[1][qt][lr]), fmaxf(redA[2][qt][lr], redA[3][qt][lr]));
    #pragma unroll
    for (int qt = 0; qt < 4; ++qt){
      float s = 0.f;
      #pragma unroll
      for (int kt = 0; kt < 4; ++kt){
        bf16x4 pk;
        #pragma unroll
        for (int e = 0; e < 4; ++e){
          float p = __expf((acc[kt][qt][e] - gm[qt]) * 0.25f);
          s += p; pk[e] = (__bf16)p;
        }
        *(bf16x4*)(P_s + (size_t)(qt * 16 + lr) * 264 + w * 64 + kt * 16 + lg * 4) = pk;
      }
      s += __shfl_xor(s, 16); s += __shfl_xor(s, 32);
      if (l < 16) redB[w][qt][lr] = s;
    }
    __syncthreads();  // #2
    if (tid < 64){
      int qt = tid >> 4, r = tid & 15;
      den[tid] = redB[0][qt][r] + redB[1][qt][r] + redB[2][qt][r] + redB[3][qt][r];
    }
    {
      f32x4 o[4];
      #pragma unroll
      for (int qt = 0; qt < 4; ++qt) o[qt] = (f32x4){0.f,0.f,0.f,0.f};
      #pragma unroll
      for (int ks = 0; ks < 2; ++ks){
        int kb = w * 64 + ks * 32;
        bf16x8 bfr2 = *(const bf16x8*)(vT_s + (size_t)lr * 264 + kb + lg * 8);
        #pragma unroll
        for (int qt = 0; qt < 4; ++qt){
          bf16x8 afr2 = *(const bf16x8*)(P_s + (size_t)(qt * 16 + lr) * 264 + kb + lg * 8);
          o[qt] = __builtin_amdgcn_mfma_f32_16x16x32_bf16(afr2, bfr2, o[qt], 0, 0, 0);
        }
      }
      #pragma unroll
      for (int qt = 0; qt < 4; ++qt)
        #pragma unroll
        for (int e = 0; e < 4; ++e)
          cpart[w][qt * 16 + lg * 4 + e][lr] = o[qt][e];
    }
    __syncthreads();  // #3
    {
      int q = tid >> 2, dg = (tid & 3) * 4;
      float inv = 1.f / den[q];
      bf16x4 ov;
      #pragma unroll
      for (int jj = 0; jj < 4; ++jj)
        ov[jj] = (__bf16)((cpart[0][q][dg+jj] + cpart[1][q][dg+jj] + cpart[2][q][dg+jj] + cpart[3][q][dg+jj]) * inv);
      *(bf16x4*)(ctx_l + (size_t)(b * LPB + q) * DMODEL + h * 16 + dg) = ov;
    }
  } else {
    // ---- protein queries (256) over ligand keys (64) ----
    int bb = bid - NBATCH * NHEAD;
    int b = bb >> 3, h = bb & 7;
    const u16* qp = qkv_p + (size_t)b * PPB * 384;
    const u16* ql = qkv_l + (size_t)b * LPB * 384;
    if (tid < 64){
      const u16* src = ql + (size_t)tid * 384 + 256 + h * 16;
      bf16x8 v0 = *(const bf16x8*)src;
      bf16x8 v1 = *(const bf16x8*)(src + 8);
      #pragma unroll
      for (int i = 0; i < 8; ++i){
        vT_s[i * 72 + tid]       = ((const u16*)&v0)[i];
        vT_s[(i + 8) * 72 + tid] = ((const u16*)&v1)[i];
      }
    }
    f32x4 acc2[4][4];
    #pragma unroll
    for (int kt = 0; kt < 4; ++kt)
      #pragma unroll
      for (int qq = 0; qq < 4; ++qq) acc2[kt][qq] = (f32x4){0.f,0.f,0.f,0.f};
    {
      bf16x8 afr[4], bfr[4];
      #pragma unroll
      for (int kt = 0; kt < 4; ++kt)
        afr[kt] = (l < 32) ? *(const bf16x8*)(ql + (size_t)(kt * 16 + lr) * 384 + 128 + h * 16 + lg * 8) : zero8;
      #pragma unroll
      for (int qq = 0; qq < 4; ++qq)
        bfr[qq] = (l < 32) ? *(const bf16x8*)(qp + (size_t)((w * 4 + qq) * 16 + lr) * 384 + h * 16 + lg * 8) : zero8;
      #pragma unroll
      for (int kt = 0; kt < 4; ++kt)
        #pragma unroll
        for (int qq = 0; qq < 4; ++qq)
          acc2[kt][qq] = __builtin_amdgcn_mfma_f32_16x16x32_bf16(afr[kt], bfr[qq], acc2[kt][qq], 0, 0, 0);
    }
    #pragma unroll
    for (int qq = 0; qq < 4; ++qq){
      float m = -1e30f;
      #pragma unroll
      for (int kt = 0; kt < 4; ++kt)
        #pragma unroll
        for (int e = 0; e < 4; ++e) m = fmaxf(m, acc2[kt][qq][e]);
      m = fmaxf(m, __shfl_xor(m, 16)); m = fmaxf(m, __shfl_xor(m, 32));
      float s = 0.f;
      #pragma unroll
      for (int kt = 0; kt < 4; ++kt){
        bf16x4 pk;
        #pragma unroll
        for (int e = 0; e < 4; ++e){
          float p = __expf((acc2[kt][qq][e] - m) * 0.25f);
          s += p; pk[e] = (__bf16)p;
        }
        *(bf16x4*)(P_s + (size_t)((w * 4 + qq) * 16 + lr) * 72 + kt * 16 + lg * 4) = pk;
      }
      s += __shfl_xor(s, 16); s += __shfl_xor(s, 32);
      if (l < 16) den[(w * 4 + qq) * 16 + lr] = s;
    }
    __syncthreads();
    {
      f32x4 o2[4];
      #pragma unroll
      for (int qq = 0; qq < 4; ++qq) o2[qq] = (f32x4){0.f,0.f,0.f,0.f};
      #pragma unroll
      for (int ks = 0; ks < 2; ++ks){
        int kb = ks * 32;
        bf16x8 bfr2 = *(const bf16x8*)(vT_s + (size_t)lr * 72 + kb + lg * 8);
        #pragma unroll
        for (int qq = 0; qq < 4; ++qq){
          bf16x8 afr2 = *(const bf16x8*)(P_s + (size_t)((w * 4 + qq) * 16 + lr) * 72 + kb + lg * 8);
          o2[qq] = __builtin_amdgcn_mfma_f32_16x16x32_bf16(afr2, bfr2, o2[qq], 0, 0, 0);
        }
      }
      #pragma unroll
      for (int qq = 0; qq < 4; ++qq)
        #pragma unroll
        for (int e = 0; e < 4; ++e){
          int q = (w * 4 + qq) * 16 + lg * 4 + e;
          ctx_p[(size_t)(b * PPB + q) * DMODEL + h * 16 + lr] = f2bf(o2[qq][e] / den[q]);
        }
    }
  }
}

// ================= L3: fused tail (512 threads, 8 waves) =================
struct TailArgs {
  const u16 *ctx_bf[2];
  const float *h_f[2];
  const u16 *WgT[2], *WgB[2], *WuT[2];
  const float *bg[2], *bu[2], *lng[2], *lnb[2];
  const u16 *W1T[2], *W2T[2];
  const float *b1[2], *b2[2];
  float* out[2];
};

__global__ __launch_bounds__(512) void tail_kernel(TailArgs args){
  __shared__ float hu_s[TR][132];
  __shared__ u16 xln_s[TR][136];
  __shared__ u16 t_s[TR][520];

  int bid = (int)blockIdx.x;
  int side = (bid < NPROT / TR) ? 0 : 1;
  int rowbase = (side ? bid - NPROT / TR : bid) * TR;
  int tid = (int)threadIdx.x;
  int w = tid >> 6;           // 0..7
  int l = tid & 63;
  int lr = l & 15;
  int lk = (l >> 4) * 8;

  // ---- stage 1: glin (K=256: h|ctx) and u (K=128: ctx); each wave owns 16 cols ----
  {
    f32x4 g0 = {0.f,0.f,0.f,0.f}, g1 = g0, u0 = g0, u1 = g0;
    const float* Ahf = args.h_f[side] + (size_t)(rowbase + lr) * 128 + lk;
    const __bf16* Ac = (const __bf16*)args.ctx_bf[side] + (size_t)(rowbase + lr) * 128 + lk;
    const __bf16* Bg = (const __bf16*)args.WgT[side] + (size_t)(w * 16 + lr) * 128 + lk;
    const __bf16* Bc = (const __bf16*)args.WgB[side] + (size_t)(w * 16 + lr) * 128 + lk;
    const __bf16* Bu = (const __bf16*)args.WuT[side] + (size_t)(w * 16 + lr) * 128 + lk;
    #pragma unroll
    for (int kk = 0; kk < 128; kk += 32){
      bf16x8 ah0 = cvt8(Ahf + kk);
      bf16x8 ah1 = cvt8(Ahf + 16 * 128 + kk);
      bf16x8 ac0 = *(const bf16x8*)(Ac + kk);
      bf16x8 ac1 = *(const bf16x8*)(Ac + 16 * 128 + kk);
      bf16x8 bg = *(const bf16x8*)(Bg + kk);
      bf16x8 bc = *(const bf16x8*)(Bc + kk);
      bf16x8 bu = *(const bf16x8*)(Bu + kk);
      g0 = __builtin_amdgcn_mfma_f32_16x16x32_bf16(ah0, bg, g0, 0, 0, 0);
      g1 = __builtin_amdgcn_mfma_f32_16x16x32_bf16(ah1, bg, g1, 0, 0, 0);
      g0 = __builtin_amdgcn_mfma_f32_16x16x32_bf16(ac0, bc, g0, 0, 0, 0);
      g1 = __builtin_amdgcn_mfma_f32_16x16x32_bf16(ac1, bc, g1, 0, 0, 0);
      u0 = __builtin_amdgcn_mfma_f32_16x16x32_bf16(ac0, bu, u0, 0, 0, 0);
      u1 = __builtin_amdgcn_mfma_f32_16x16x32_bf16(ac1, bu, u1, 0, 0, 0);
    }
    const float* hf = args.h_f[side];
    const float* bgv = args.bg[side];
    const float* buv = args.bu[side];
    int col = w * 16 + lr;
    float bgc = bgv[col], buc = buv[col];
    #pragma unroll
    for (int i = 0; i < 2; ++i){
      f32x4 gv4 = i ? g1 : g0;
      f32x4 uv4 = i ? u1 : u0;
      #pragma unroll
      for (int e = 0; e < 4; ++e){
        int row = i * 16 + ((l >> 4) << 2) + e;
        float gv = gv4[e] + bgc;
        float uv = uv4[e] + buc;
        float hv = hf[(size_t)(rowbase + row) * 128 + col];
        float sg = 1.f / (1.f + __expf(-gv));
        hu_s[row][col] = hv + sg * uv;
      }
    }
  }
  __syncthreads();

  // ---- stage 2: LayerNorm -> xln (bf16, XOR-swizzled); 16 threads per row ----
  {
    int r = tid >> 4;
    int sub = tid & 15;
    float x[8];
    #pragma unroll
    for (int i = 0; i < 2; ++i){
      float4 v4 = *(const float4*)&hu_s[r][sub * 8 + i * 4];
      x[i*4+0] = v4.x; x[i*4+1] = v4.y; x[i*4+2] = v4.z; x[i*4+3] = v4.w;
    }
    float s = 0.f;
    #pragma unroll
    for (int i = 0; i < 8; ++i) s += x[i];
    s += __shfl_xor(s, 1); s += __shfl_xor(s, 2); s += __shfl_xor(s, 4); s += __shfl_xor(s, 8);
    float mu = s * (1.f / 128.f);
    float vv = 0.f;
    #pragma unroll
    for (int i = 0; i < 8; ++i){ float d = x[i] - mu; vv += d * d; }
    vv += __shfl_xor(vv, 1); vv += __shfl_xor(vv, 2); vv += __shfl_xor(vv, 4); vv += __shfl_xor(vv, 8);
    float rs = rsqrtf(vv * (1.f / 128.f) + 1e-5f);
    const float* lg2 = args.lng[side];
    const float* lb = args.lnb[side];
    int sw = (r & 7) << 3;
    #pragma unroll
    for (int i = 0; i < 8; ++i){
      int col = sub * 8 + i;
      xln_s[r][col ^ sw] = f2bf((x[i] - mu) * rs * lg2[col] + lb[col]);
    }
  }
  __syncthreads();

  // ---- stage 3: FFN1 t = relu(xln @ W1 + b1); each wave owns 64 cols ----
  {
    f32x4 acc[2][4];
    #pragma unroll
    for (int i = 0; i < 2; ++i)
      #pragma unroll
      for (int jj = 0; jj < 4; ++jj) acc[i][jj] = (f32x4){0.f,0.f,0.f,0.f};
    const __bf16* B1 = (const __bf16*)args.W1T[side] + (size_t)(w * 64 + lr) * 128 + lk;
    int sw0 = (lr & 7) << 3;
    #pragma unroll
    for (int kk = 0; kk < 128; kk += 32){
      bf16x8 a0 = *(const bf16x8*)&xln_s[lr][(kk + lk) ^ sw0];
      bf16x8 a1 = *(const bf16x8*)&xln_s[16 + lr][(kk + lk) ^ sw0];
      #pragma unroll
      for (int jj = 0; jj < 4; ++jj){
        bf16x8 bb = *(const bf16x8*)(B1 + (size_t)jj * 16 * 128 + kk);
        acc[0][jj] = __builtin_amdgcn_mfma_f32_16x16x32_bf16(a0, bb, acc[0][jj], 0, 0, 0);
        acc[1][jj] = __builtin_amdgcn_mfma_f32_16x16x32_bf16(a1, bb, acc[1][jj], 0, 0, 0);
      }
    }
    const float* b1v = args.b1[side];
    #pragma unroll
    for (int i = 0; i < 2; ++i)
      #pragma unroll
      for (int jj = 0; jj < 4; ++jj)
        #pragma unroll
        for (int e = 0; e < 4; ++e){
          int row = i * 16 + ((l >> 4) << 2) + e;
          int col = w * 64 + jj * 16 + lr;
          float v = fmaxf(acc[i][jj][e] + b1v[col], 0.f);
          t_s[row][col ^ ((row & 7) << 3)] = f2bf(v);
        }
  }
  __syncthreads();

  // ---- stage 4: FFN2 out = t @ W2 + b2 + hu; each wave owns 16 cols ----
  {
    f32x4 o0 = {0.f,0.f,0.f,0.f}, o1 = o0;
    const __bf16* B2 = (const __bf16*)args.W2T[side] + (size_t)(w * 16 + lr) * 512 + lk;
    int sw0 = (lr & 7) << 3;
    #pragma unroll
    for (int kk = 0; kk < 512; kk += 32){
      bf16x8 a0 = *(const bf16x8*)&t_s[lr][(kk + lk) ^ sw0];
      bf16x8 a1 = *(const bf16x8*)&t_s[16 + lr][(kk + lk) ^ sw0];
      bf16x8 bb = *(const bf16x8*)(B2 + kk);
      o0 = __builtin_amdgcn_mfma_f32_16x16x32_bf16(a0, bb, o0, 0, 0, 0);
      o1 = __builtin_amdgcn_mfma_f32_16x16x32_bf16(a1, bb, o1, 0, 0, 0);
    }
    const float* b2v = args.b2[side];
    float* outp = args.out[side];
    int col = w * 16 + lr;
    float b2c = b2v[col];
    #pragma unroll
    for (int i = 0; i < 2; ++i){
      f32x4 ov4 = i ? o1 : o0;
      #pragma unroll
      for (int e = 0; e < 4; ++e){
        int row = i * 16 + ((l >> 4) << 2) + e;
        outp[(size_t)(rowbase + row) * 128 + col] = ov4[e] + b2c + hu_s[row][col];
      }
    }
  }
}

// ================= host =================
extern "C" void kernel_launch(void* const* d_in, const int* in_sizes, int n_in,
                              void* d_out, int out_size, void* d_ws, size_t ws_size,
                              hipStream_t stream) {
  (void)in_sizes; (void)n_in; (void)out_size; (void)ws_size;
  const float* h_p  = (const float*)d_in[0];
  const float* h_l  = (const float*)d_in[1];
  const float* Wq_l = (const float*)d_in[4];
  const float* Wk_p = (const float*)d_in[5];
  const float* Wv_p = (const float*)d_in[6];
  const float* Wg_l = (const float*)d_in[7];
  const float* bg_l = (const float*)d_in[8];
  const float* Wu_l = (const float*)d_in[9];
  const float* bu_l = (const float*)d_in[10];
  const float* Wq_p = (const float*)d_in[11];
  const float* Wk_l = (const float*)d_in[12];
  const float* Wv_l = (const float*)d_in[13];
  const float* Wg_p = (const float*)d_in[14];
  const float* bg_p = (const float*)d_in[15];
  const float* Wu_p = (const float*)d_in[16];
  const float* bu_p = (const float*)d_in[17];
  const float* ln_p_g = (const float*)d_in[18];
  const float* ln_p_b = (const float*)d_in[19];
  const float* ln_l_g = (const float*)d_in[20];
  const float* ln_l_b = (const float*)d_in[21];
  const float* W1_p = (const float*)d_in[22];
  const float* b1_p = (const float*)d_in[23];
  const float* W2_p = (const float*)d_in[24];
  const float* b2_p = (const float*)d_in[25];
  const float* W1_l = (const float*)d_in[26];
  const float* b1_l = (const float*)d_in[27];
  const float* W2_l = (const float*)d_in[28];
  const float* b2_l = (const float*)d_in[29];
  float* out = (float*)d_out;

  char* ws = (char*)d_ws;
  size_t off = 0;
  auto alloc = [&](size_t bytes) -> void* {
    void* p = ws + off; off += (bytes + 255) & ~(size_t)255; return p;
  };
  u16* WgT_p_T = (u16*)alloc((size_t)128 * 128 * 2);
  u16* WgB_p_T = (u16*)alloc((size_t)128 * 128 * 2);
  u16* Wu_p_T  = (u16*)alloc((size_t)128 * 128 * 2);
  u16* WgT_l_T = (u16*)alloc((size_t)128 * 128 * 2);
  u16* WgB_l_T = (u16*)alloc((size_t)128 * 128 * 2);
  u16* Wu_l_T  = (u16*)alloc((size_t)128 * 128 * 2);
  u16* W1_p_T  = (u16*)alloc((size_t)512 * 128 * 2);
  u16* W1_l_T  = (u16*)alloc((size_t)512 * 128 * 2);
  u16* W2_p_T  = (u16*)alloc((size_t)128 * 512 * 2);
  u16* W2_l_T  = (u16*)alloc((size_t)128 * 512 * 2);
  u16* qkv_p   = (u16*)alloc((size_t)NPROT * 384 * 2);
  u16* qkv_l   = (u16*)alloc((size_t)NLIG  * 384 * 2);
  u16* ctx_p_bf = (u16*)alloc((size_t)NPROT * DMODEL * 2);
  u16* ctx_l_bf = (u16*)alloc((size_t)NLIG  * DMODEL * 2);

  // ---- L1: qkv + prep ----
  {
    L1Args a;
    a.qjobs[0] = { h_p, {Wq_p, Wk_p, Wv_p}, qkv_p, 0 };
    a.qjobs[1] = { h_l, {Wq_l, Wk_l, Wv_l}, qkv_l, (NPROT / 64) * 6 };
    a.nQkv = (NPROT / 64) * 6 + (NLIG / 64) * 6;   // 960
    int pbs = 0;
    int pi = 0;
    auto addT = [&](const float* s, u16* d, int K, int M){
      a.pjobs[pi].src = s; a.pjobs[pi].dst = d; a.pjobs[pi].M = M; a.pjobs[pi].K = K;
      a.pjobs[pi].tilesX = M / 32; a.pjobs[pi].blockStart = pbs;
      pbs += (K / 32) * (M / 32); ++pi;
    };
    addT(Wg_l,             WgT_l_T, 128, 128);
    addT(Wg_l + 128 * 128, WgB_l_T, 128, 128);
    addT(Wu_l,             Wu_l_T,  128, 128);
    addT(Wg_p,             WgT_p_T, 128, 128);
    addT(Wg_p + 128 * 128, WgB_p_T, 128, 128);
    addT(Wu_p,             Wu_p_T,  128, 128);
    addT(W1_p, W1_p_T, 128, 512);
    addT(W2_p, W2_p_T, 512, 128);
    addT(W1_l, W1_l_T, 128, 512);
    addT(W2_l, W2_l_T, 512, 128);
    a.nprep = pi;
    l1_kernel<<<dim3(a.nQkv + pbs), dim3(256), 0, stream>>>(a);
  }

  // ---- L2: attention (both directions, separate blocks) ----
  attn_kernel<<<dim3(2 * NBATCH * NHEAD), dim3(256), 0, stream>>>(qkv_p, qkv_l, ctx_p_bf, ctx_l_bf);

  // ---- L3: fused tail ----
  {
    TailArgs tl;
    tl.ctx_bf[0] = ctx_p_bf; tl.ctx_bf[1] = ctx_l_bf;
    tl.h_f[0] = h_p; tl.h_f[1] = h_l;
    tl.WgT[0] = WgT_p_T; tl.WgT[1] = WgT_l_T;
    tl.WgB[0] = WgB_p_T; tl.WgB[1] = WgB_l_T;
    tl.WuT[0] = Wu_p_T;  tl.WuT[1] = Wu_l_T;
    tl.bg[0] = bg_p; tl.bg[1] = bg_l;
    tl.bu[0] = bu_p; tl.bu[1] = bu_l;
    tl.lng[0] = ln_p_g; tl.lng[1] = ln_l_g;
    tl.lnb[0] = ln_p_b; tl.lnb[1] = ln_l_b;
    tl.W1T[0] = W1_p_T; tl.W1T[1] = W1_l_T;
    tl.W2T[0] = W2_p_T; tl.W2T[1] = W2_l_T;
    tl.b1[0] = b1_p; tl.b1[1] = b1_l;
    tl.b2[0] = b2_p; tl.b2[1] = b2_l;
    tl.out[0] = out; tl.out[1] = out + (size_t)NPROT * DMODEL;
    tail_kernel<<<dim3(NPROT / TR + NLIG / TR), dim3(512), 0, stream>>>(tl);
  }
}

// Round 5
// 63.611 us; speedup vs baseline: 1.0652x; 1.0652x over previous
//
#include <hip/hip_runtime.h>
#include <hip/hip_bf16.h>

typedef __bf16 bf16x8 __attribute__((ext_vector_type(8)));
typedef __bf16 bf16x4 __attribute__((ext_vector_type(4)));
typedef float  f32x4  __attribute__((ext_vector_type(4)));
typedef unsigned short u16;

#define NPROT 8192
#define NLIG  2048
#define DMODEL 128
#define NHEAD 8
#define NBATCH 32
#define PPB 256
#define LPB 64
#define TR 32

__device__ __forceinline__ u16 f2bf(float f){
  union { float f; unsigned int u; } v; v.f = f;
  return (u16)((v.u + 0x7FFFu + ((v.u >> 16) & 1u)) >> 16);
}

__device__ __forceinline__ bf16x8 cvt8(const float* p){
  float4 a = *(const float4*)p, b = *(const float4*)(p + 4);
  bf16x8 r;
  r[0]=(__bf16)a.x; r[1]=(__bf16)a.y; r[2]=(__bf16)a.z; r[3]=(__bf16)a.w;
  r[4]=(__bf16)b.x; r[5]=(__bf16)b.y; r[6]=(__bf16)b.z; r[7]=(__bf16)b.w;
  return r;
}

// ================= K1: qkv GEMM (self-transposing W) + prep transpose blocks =================
struct QkvJob { const float* A; const float* Wsrc[3]; u16* outB; int blockStart; };
struct TJob { const float* src; u16* dst; int M, K, tilesX, blockStart; };
struct L1Args {
  QkvJob qjobs[2];
  int nQkv;
  int nprep;
  TJob pjobs[10];
};

__global__ __launch_bounds__(256) void l1_kernel(L1Args a){
  __shared__ u16 Wl[64][136];
  __shared__ float tile[32][33];
  int bid = (int)blockIdx.x;
  int tid = (int)threadIdx.x;
  if (bid < a.nQkv){
    int j = (bid >= a.qjobs[1].blockStart) ? 1 : 0;
    const QkvJob jb = a.qjobs[j];
    int t = bid - jb.blockStart;
    int tn = t / 6, tm = t - tn * 6;
    {
      int midx = tm >> 1;
      int cb64 = (tm & 1) * 64;
      const float* Ws = jb.Wsrc[midx];
      int kr = tid >> 2;
      int cb = (tid & 3) * 16;
      #pragma unroll
      for (int p = 0; p < 2; ++p){
        int k = p * 64 + kr;
        const float* srcp = Ws + (size_t)k * 128 + cb64 + cb;
        float4 v0 = *(const float4*)srcp,     v1 = *(const float4*)(srcp + 4);
        float4 v2 = *(const float4*)(srcp+8), v3 = *(const float4*)(srcp + 12);
        float tmp[16] = {v0.x,v0.y,v0.z,v0.w, v1.x,v1.y,v1.z,v1.w,
                         v2.x,v2.y,v2.z,v2.w, v3.x,v3.y,v3.z,v3.w};
        #pragma unroll
        for (int i = 0; i < 16; ++i) Wl[cb + i][k] = f2bf(tmp[i]);
      }
    }
    __syncthreads();
    int w = tid >> 6, l = tid & 63;
    int roff = tn * 64 + (w >> 1) * 32;
    int cloc = (w & 1) * 32;
    int lr = l & 15, lk = (l >> 4) * 8;
    f32x4 a00 = {0.f,0.f,0.f,0.f}, a01 = a00, a10 = a00, a11 = a00;
    const float* Af  = jb.A + (size_t)(roff + lr) * 128 + lk;
    const float* Af2 = Af + 16 * 128;
    #pragma unroll
    for (int kk = 0; kk < 128; kk += 32){
      bf16x8 a0 = cvt8(Af + kk);
      bf16x8 a1 = cvt8(Af2 + kk);
      bf16x8 b0 = *(const bf16x8*)&Wl[cloc + lr][kk + lk];
      bf16x8 b1 = *(const bf16x8*)&Wl[cloc + 16 + lr][kk + lk];
      a00 = __builtin_amdgcn_mfma_f32_16x16x32_bf16(a0, b0, a00, 0, 0, 0);
      a01 = __builtin_amdgcn_mfma_f32_16x16x32_bf16(a0, b1, a01, 0, 0, 0);
      a10 = __builtin_amdgcn_mfma_f32_16x16x32_bf16(a1, b0, a10, 0, 0, 0);
      a11 = __builtin_amdgcn_mfma_f32_16x16x32_bf16(a1, b1, a11, 0, 0, 0);
    }
    int rbase = roff + ((l >> 4) << 2);
    f32x4 av[2][2] = {{a00, a01}, {a10, a11}};
    #pragma unroll
    for (int i = 0; i < 2; ++i)
      #pragma unroll
      for (int jj = 0; jj < 2; ++jj)
        #pragma unroll
        for (int e = 0; e < 4; ++e){
          int rr = rbase + i * 16 + e;
          int cc = tm * 64 + cloc + jj * 16 + lr;
          jb.outB[(size_t)rr * 384 + cc] = f2bf(av[i][jj][e]);
        }
  } else {
    int pb = bid - a.nQkv;
    int j = 0;
    while (j + 1 < a.nprep && pb >= a.pjobs[j + 1].blockStart) ++j;
    const TJob jb = a.pjobs[j];
    int t = pb - jb.blockStart;
    int tm = t % jb.tilesX, tk = t / jb.tilesX;
    int c = tid & 31, r0 = tid >> 5;
    #pragma unroll
    for (int p = 0; p < 4; ++p)
      tile[r0 + p * 8][c] = jb.src[(size_t)(tk * 32 + r0 + p * 8) * jb.M + tm * 32 + c];
    __syncthreads();
    #pragma unroll
    for (int p = 0; p < 4; ++p)
      jb.dst[(size_t)(tm * 32 + r0 + p * 8) * jb.K + tk * 32 + c] = f2bf(tile[c][r0 + p * 8]);
  }
}

// ================= K2: per-stripe fused attention + gate + LN + FFN =================
struct K2Args {
  const u16 *qkv_p, *qkv_l;
  const float *h_f[2];
  const u16 *WgT[2], *WgB[2], *WuT[2];
  const float *bg[2], *bu[2], *lng[2], *lnb[2];
  const u16 *W1T[2], *W2T[2];
  const float *b1[2], *b2[2];
  float* out[2];
};

__global__ __launch_bounds__(256) void k2_kernel(K2Args args){
  __shared__ __align__(16) union {
    struct { u16 vT[4][1152]; u16 P[4][2304]; } a;   // wave-private V^T [16][72] / P [32][72]
    u16 t[32 * 520];                                  // FFN1 activations (reused region)
  } su;
  __shared__ __align__(16) u16 s_ctx[32 * 128];       // swizzled ctx, later reused as xln
  __shared__ float hu_s[32][132];

  int bid = (int)blockIdx.x;
  int tid = (int)threadIdx.x;
  int w = tid >> 6, l = tid & 63, lr = l & 15, lg4 = l >> 4;
  int lk = lg4 * 8;

  int side, rowbase, batch, NC;
  if (bid < NLIG / TR){ side = 1; rowbase = bid * TR; batch = rowbase >> 6; NC = 4; }
  else { side = 0; rowbase = (bid - NLIG / TR) * TR; batch = rowbase >> 8; NC = 1; }

  const u16* qrow = (side == 0 ? args.qkv_p : args.qkv_l) + (size_t)rowbase * 384;
  const u16* orow = (side == 0 ? args.qkv_l : args.qkv_p)
                    + (size_t)(side == 0 ? batch * LPB : batch * PPB) * 384;

  bf16x8 zero8;
  #pragma unroll
  for (int i = 0; i < 8; ++i) zero8[i] = (__bf16)0.f;

  u16* vTw = su.a.vT[w];
  u16* Pw  = su.a.P[w];

  // ---- attention: each wave owns heads {2w, 2w+1}; online softmax over 64-key chunks ----
  for (int hh = 0; hh < 2; ++hh){
    int h = w * 2 + hh;
    bf16x8 qf[2];
    #pragma unroll
    for (int qt = 0; qt < 2; ++qt)
      qf[qt] = (l < 32) ? *(const bf16x8*)(qrow + (size_t)(qt * 16 + lr) * 384 + h * 16 + lk) : zero8;
    f32x4 Ot[2]; float mv[2], ls[2];
    #pragma unroll
    for (int qt = 0; qt < 2; ++qt){ Ot[qt] = (f32x4){0.f,0.f,0.f,0.f}; mv[qt] = -1e30f; ls[qt] = 0.f; }
    for (int c = 0; c < NC; ++c){
      // stage V^T chunk (wave-private): key = c*64 + l
      {
        const u16* vs = orow + (size_t)(c * 64 + l) * 384 + 256 + h * 16;
        bf16x8 v0 = *(const bf16x8*)vs;
        bf16x8 v1 = *(const bf16x8*)(vs + 8);
        #pragma unroll
        for (int i = 0; i < 8; ++i){
          vTw[i * 72 + l]       = ((const u16*)&v0)[i];
          vTw[(i + 8) * 72 + l] = ((const u16*)&v1)[i];
        }
      }
      bf16x8 kf[4];
      #pragma unroll
      for (int kt = 0; kt < 4; ++kt)
        kf[kt] = (l < 32) ? *(const bf16x8*)(orow + (size_t)(c * 64 + kt * 16 + lr) * 384 + 128 + h * 16 + lk) : zero8;
      f32x4 sa[4][2];
      #pragma unroll
      for (int kt = 0; kt < 4; ++kt)
        #pragma unroll
        for (int qt = 0; qt < 2; ++qt)
          sa[kt][qt] = __builtin_amdgcn_mfma_f32_16x16x32_bf16(kf[kt], qf[qt], (f32x4){0.f,0.f,0.f,0.f}, 0, 0, 0);
      // online softmax update + P chunk write (wave-private)
      #pragma unroll
      for (int qt = 0; qt < 2; ++qt){
        float cm = -1e30f;
        #pragma unroll
        for (int kt = 0; kt < 4; ++kt)
          #pragma unroll
          for (int e = 0; e < 4; ++e) cm = fmaxf(cm, sa[kt][qt][e]);
        cm = fmaxf(cm, __shfl_xor(cm, 16)); cm = fmaxf(cm, __shfl_xor(cm, 32));
        float mn = fmaxf(mv[qt], cm);
        float resc = __expf((mv[qt] - mn) * 0.25f);
        mv[qt] = mn;
        float cs = 0.f;
        #pragma unroll
        for (int kt = 0; kt < 4; ++kt){
          bf16x4 pk;
          #pragma unroll
          for (int e = 0; e < 4; ++e){
            float p = __expf((sa[kt][qt][e] - mn) * 0.25f);
            cs += p; pk[e] = (__bf16)p;
          }
          *(bf16x4*)&Pw[(size_t)(qt * 16 + lr) * 72 + kt * 16 + lg4 * 4] = pk;
        }
        cs += __shfl_xor(cs, 16); cs += __shfl_xor(cs, 32);
        ls[qt] = ls[qt] * resc + cs;
        Ot[qt] = Ot[qt] * resc;
      }
      // PV over this chunk (wave-private LDS; compiler inserts lgkmcnt)
      #pragma unroll
      for (int ks = 0; ks < 2; ++ks){
        bf16x8 va = *(const bf16x8*)&vTw[(size_t)lr * 72 + ks * 32 + lg4 * 8];
        #pragma unroll
        for (int qt = 0; qt < 2; ++qt){
          bf16x8 pb = *(const bf16x8*)&Pw[(size_t)(qt * 16 + lr) * 72 + ks * 32 + lg4 * 8];
          Ot[qt] = __builtin_amdgcn_mfma_f32_16x16x32_bf16(va, pb, Ot[qt], 0, 0, 0);
        }
      }
    }
    // finalize: ctx[q][h*16+d] (XOR-swizzled row-wise)
    #pragma unroll
    for (int qt = 0; qt < 2; ++qt){
      float inv = 1.f / ls[qt];
      int q = qt * 16 + lr;
      int dbase = h * 16 + lg4 * 4;
      bf16x4 ov;
      #pragma unroll
      for (int e = 0; e < 4; ++e) ov[e] = (__bf16)(Ot[qt][e] * inv);
      *(bf16x4*)&s_ctx[(size_t)q * 128 + (dbase ^ ((q & 7) << 3))] = ov;
    }
  }
  __syncthreads();

  // ---- stage 1: glin (K=256: h|ctx) and u (K=128: ctx); 4 waves × 32 cols ----
  {
    f32x4 g[2][2], u[2][2];
    #pragma unroll
    for (int i = 0; i < 2; ++i)
      #pragma unroll
      for (int jj = 0; jj < 2; ++jj){ g[i][jj] = (f32x4){0.f,0.f,0.f,0.f}; u[i][jj] = g[i][jj]; }
    const float* Ahf = args.h_f[side] + (size_t)(rowbase + lr) * 128 + lk;
    const __bf16* Bg = (const __bf16*)args.WgT[side] + (size_t)(w * 32 + lr) * 128 + lk;
    const __bf16* Bc = (const __bf16*)args.WgB[side] + (size_t)(w * 32 + lr) * 128 + lk;
    const __bf16* Bu = (const __bf16*)args.WuT[side] + (size_t)(w * 32 + lr) * 128 + lk;
    int swa = (lr & 7) << 3;
    #pragma unroll
    for (int kk = 0; kk < 128; kk += 32){
      bf16x8 ah0 = cvt8(Ahf + kk);
      bf16x8 ah1 = cvt8(Ahf + 16 * 128 + kk);
      bf16x8 ac0 = *(const bf16x8*)&s_ctx[(size_t)lr * 128 + ((kk + lk) ^ swa)];
      bf16x8 ac1 = *(const bf16x8*)&s_ctx[(size_t)(16 + lr) * 128 + ((kk + lk) ^ swa)];
      bf16x8 bg0 = *(const bf16x8*)(Bg + kk);
      bf16x8 bg1 = *(const bf16x8*)(Bg + 16 * 128 + kk);
      bf16x8 bc0 = *(const bf16x8*)(Bc + kk);
      bf16x8 bc1 = *(const bf16x8*)(Bc + 16 * 128 + kk);
      bf16x8 bu0 = *(const bf16x8*)(Bu + kk);
      bf16x8 bu1 = *(const bf16x8*)(Bu + 16 * 128 + kk);
      g[0][0] = __builtin_amdgcn_mfma_f32_16x16x32_bf16(ah0, bg0, g[0][0], 0, 0, 0);
      g[0][1] = __builtin_amdgcn_mfma_f32_16x16x32_bf16(ah0, bg1, g[0][1], 0, 0, 0);
      g[1][0] = __builtin_amdgcn_mfma_f32_16x16x32_bf16(ah1, bg0, g[1][0], 0, 0, 0);
      g[1][1] = __builtin_amdgcn_mfma_f32_16x16x32_bf16(ah1, bg1, g[1][1], 0, 0, 0);
      g[0][0] = __builtin_amdgcn_mfma_f32_16x16x32_bf16(ac0, bc0, g[0][0], 0, 0, 0);
      g[0][1] = __builtin_amdgcn_mfma_f32_16x16x32_bf16(ac0, bc1, g[0][1], 0, 0, 0);
      g[1][0] = __builtin_amdgcn_mfma_f32_16x16x32_bf16(ac1, bc0, g[1][0], 0, 0, 0);
      g[1][1] = __builtin_amdgcn_mfma_f32_16x16x32_bf16(ac1, bc1, g[1][1], 0, 0, 0);
      u[0][0] = __builtin_amdgcn_mfma_f32_16x16x32_bf16(ac0, bu0, u[0][0], 0, 0, 0);
      u[0][1] = __builtin_amdgcn_mfma_f32_16x16x32_bf16(ac0, bu1, u[0][1], 0, 0, 0);
      u[1][0] = __builtin_amdgcn_mfma_f32_16x16x32_bf16(ac1, bu0, u[1][0], 0, 0, 0);
      u[1][1] = __builtin_amdgcn_mfma_f32_16x16x32_bf16(ac1, bu1, u[1][1], 0, 0, 0);
    }
    const float* hf = args.h_f[side];
    const float* bgv = args.bg[side];
    const float* buv = args.bu[side];
    #pragma unroll
    for (int i = 0; i < 2; ++i)
      #pragma unroll
      for (int jj = 0; jj < 2; ++jj)
        #pragma unroll
        for (int e = 0; e < 4; ++e){
          int row = i * 16 + lg4 * 4 + e;
          int col = w * 32 + jj * 16 + lr;
          float gv = g[i][jj][e] + bgv[col];
          float uv = u[i][jj][e] + buv[col];
          float hv = hf[(size_t)(rowbase + row) * 128 + col];
          float sg = 1.f / (1.f + __expf(-gv));
          hu_s[row][col] = hv + sg * uv;
        }
  }
  __syncthreads();

  // ---- stage 2: LayerNorm -> xln (bf16, swizzled, overwrites s_ctx) ----
  {
    int r = tid >> 3;
    int sub = tid & 7;
    float x[16];
    #pragma unroll
    for (int i = 0; i < 4; ++i){
      float4 v4 = *(const float4*)&hu_s[r][sub * 16 + i * 4];
      x[i*4+0] = v4.x; x[i*4+1] = v4.y; x[i*4+2] = v4.z; x[i*4+3] = v4.w;
    }
    float s = 0.f;
    #pragma unroll
    for (int i = 0; i < 16; ++i) s += x[i];
    s += __shfl_xor(s, 1); s += __shfl_xor(s, 2); s += __shfl_xor(s, 4);
    float mu = s * (1.f / 128.f);
    float vv = 0.f;
    #pragma unroll
    for (int i = 0; i < 16; ++i){ float d = x[i] - mu; vv += d * d; }
    vv += __shfl_xor(vv, 1); vv += __shfl_xor(vv, 2); vv += __shfl_xor(vv, 4);
    float rs = rsqrtf(vv * (1.f / 128.f) + 1e-5f);
    const float* lg2 = args.lng[side];
    const float* lb = args.lnb[side];
    int sw = (r & 7) << 3;
    #pragma unroll
    for (int i = 0; i < 16; ++i){
      int col = sub * 16 + i;
      s_ctx[(size_t)r * 128 + (col ^ sw)] = f2bf((x[i] - mu) * rs * lg2[col] + lb[col]);
    }
  }
  __syncthreads();

  // ---- stage 3: FFN1 t = relu(xln @ W1 + b1); 4 waves × 128 cols ----
  {
    f32x4 acc[2][8];
    #pragma unroll
    for (int i = 0; i < 2; ++i)
      #pragma unroll
      for (int jj = 0; jj < 8; ++jj) acc[i][jj] = (f32x4){0.f,0.f,0.f,0.f};
    const __bf16* B1 = (const __bf16*)args.W1T[side] + (size_t)(w * 128 + lr) * 128 + lk;
    int sw0 = (lr & 7) << 3;
    #pragma unroll
    for (int kk = 0; kk < 128; kk += 32){
      bf16x8 a0 = *(const bf16x8*)&s_ctx[(size_t)lr * 128 + ((kk + lk) ^ sw0)];
      bf16x8 a1 = *(const bf16x8*)&s_ctx[(size_t)(16 + lr) * 128 + ((kk + lk) ^ sw0)];
      #pragma unroll
      for (int jj = 0; jj < 8; ++jj){
        bf16x8 bb = *(const bf16x8*)(B1 + (size_t)jj * 16 * 128 + kk);
        acc[0][jj] = __builtin_amdgcn_mfma_f32_16x16x32_bf16(a0, bb, acc[0][jj], 0, 0, 0);
        acc[1][jj] = __builtin_amdgcn_mfma_f32_16x16x32_bf16(a1, bb, acc[1][jj], 0, 0, 0);
      }
    }
    const float* b1v = args.b1[side];
    #pragma unroll
    for (int i = 0; i < 2; ++i)
      #pragma unroll
      for (int jj = 0; jj < 8; ++jj)
        #pragma unroll
        for (int e = 0; e < 4; ++e){
          int row = i * 16 + lg4 * 4 + e;
          int col = w * 128 + jj * 16 + lr;
          float v = fmaxf(acc[i][jj][e] + b1v[col], 0.f);
          su.t[(size_t)row * 520 + (col ^ ((row & 7) << 3))] = f2bf(v);
        }
  }
  __syncthreads();

  // ---- stage 4: FFN2 out = t @ W2 + b2 + hu; 4 waves × 32 cols ----
  {
    f32x4 o[2][2];
    #pragma unroll
    for (int i = 0; i < 2; ++i)
      #pragma unroll
      for (int jj = 0; jj < 2; ++jj) o[i][jj] = (f32x4){0.f,0.f,0.f,0.f};
    const __bf16* B2 = (const __bf16*)args.W2T[side] + (size_t)(w * 32 + lr) * 512 + lk;
    int sw0 = (lr & 7) << 3;
    #pragma unroll
    for (int kk = 0; kk < 512; kk += 32){
      bf16x8 a0 = *(const bf16x8*)&su.t[(size_t)lr * 520 + ((kk + lk) ^ sw0)];
      bf16x8 a1 = *(const bf16x8*)&su.t[(size_t)(16 + lr) * 520 + ((kk + lk) ^ sw0)];
      bf16x8 b0 = *(const bf16x8*)(B2 + kk);
      bf16x8 b1 = *(const bf16x8*)(B2 + (size_t)16 * 512 + kk);
      o[0][0] = __builtin_amdgcn_mfma_f32_16x16x32_bf16(a0, b0, o[0][0], 0, 0, 0);
      o[0][1] = __builtin_amdgcn_mfma_f32_16x16x32_bf16(a0, b1, o[0][1], 0, 0, 0);
      o[1][0] = __builtin_amdgcn_mfma_f32_16x16x32_bf16(a1, b0, o[1][0], 0, 0, 0);
      o[1][1] = __builtin_amdgcn_mfma_f32_16x16x32_bf16(a1, b1, o[1][1], 0, 0, 0);
    }
    const float* b2v = args.b2[side];
    float* outp = args.out[side];
    #pragma unroll
    for (int i = 0; i < 2; ++i)
      #pragma unroll
      for (int jj = 0; jj < 2; ++jj)
        #pragma unroll
        for (int e = 0; e < 4; ++e){
          int row = i * 16 + lg4 * 4 + e;
          int col = w * 32 + jj * 16 + lr;
          outp[(size_t)(rowbase + row) * 128 + col] = o[i][jj][e] + b2v[col] + hu_s[row][col];
        }
  }
}

// ================= host =================
extern "C" void kernel_launch(void* const* d_in, const int* in_sizes, int n_in,
                              void* d_out, int out_size, void* d_ws, size_t ws_size,
                              hipStream_t stream) {
  (void)in_sizes; (void)n_in; (void)out_size; (void)ws_size;
  const float* h_p  = (const float*)d_in[0];
  const float* h_l  = (const float*)d_in[1];
  const float* Wq_l = (const float*)d_in[4];
  const float* Wk_p = (const float*)d_in[5];
  const float* Wv_p = (const float*)d_in[6];
  const float* Wg_l = (const float*)d_in[7];
  const float* bg_l = (const float*)d_in[8];
  const float* Wu_l = (const float*)d_in[9];
  const float* bu_l = (const float*)d_in[10];
  const float* Wq_p = (const float*)d_in[11];
  const float* Wk_l = (const float*)d_in[12];
  const float* Wv_l = (const float*)d_in[13];
  const float* Wg_p = (const float*)d_in[14];
  const float* bg_p = (const float*)d_in[15];
  const float* Wu_p = (const float*)d_in[16];
  const float* bu_p = (const float*)d_in[17];
  const float* ln_p_g = (const float*)d_in[18];
  const float* ln_p_b = (const float*)d_in[19];
  const float* ln_l_g = (const float*)d_in[20];
  const float* ln_l_b = (const float*)d_in[21];
  const float* W1_p = (const float*)d_in[22];
  const float* b1_p = (const float*)d_in[23];
  const float* W2_p = (const float*)d_in[24];
  const float* b2_p = (const float*)d_in[25];
  const float* W1_l = (const float*)d_in[26];
  const float* b1_l = (const float*)d_in[27];
  const float* W2_l = (const float*)d_in[28];
  const float* b2_l = (const float*)d_in[29];
  float* out = (float*)d_out;

  char* ws = (char*)d_ws;
  size_t off = 0;
  auto alloc = [&](size_t bytes) -> void* {
    void* p = ws + off; off += (bytes + 255) & ~(size_t)255; return p;
  };
  u16* WgT_p_T = (u16*)alloc((size_t)128 * 128 * 2);
  u16* WgB_p_T = (u16*)alloc((size_t)128 * 128 * 2);
  u16* Wu_p_T  = (u16*)alloc((size_t)128 * 128 * 2);
  u16* WgT_l_T = (u16*)alloc((size_t)128 * 128 * 2);
  u16* WgB_l_T = (u16*)alloc((size_t)128 * 128 * 2);
  u16* Wu_l_T  = (u16*)alloc((size_t)128 * 128 * 2);
  u16* W1_p_T  = (u16*)alloc((size_t)512 * 128 * 2);
  u16* W1_l_T  = (u16*)alloc((size_t)512 * 128 * 2);
  u16* W2_p_T  = (u16*)alloc((size_t)128 * 512 * 2);
  u16* W2_l_T  = (u16*)alloc((size_t)128 * 512 * 2);
  u16* qkv_p   = (u16*)alloc((size_t)NPROT * 384 * 2);
  u16* qkv_l   = (u16*)alloc((size_t)NLIG  * 384 * 2);

  // ---- K1: qkv + prep ----
  {
    L1Args a;
    a.qjobs[0] = { h_p, {Wq_p, Wk_p, Wv_p}, qkv_p, 0 };
    a.qjobs[1] = { h_l, {Wq_l, Wk_l, Wv_l}, qkv_l, (NPROT / 64) * 6 };
    a.nQkv = (NPROT / 64) * 6 + (NLIG / 64) * 6;   // 960
    int pbs = 0;
    int pi = 0;
    auto addT = [&](const float* s, u16* d, int K, int M){
      a.pjobs[pi].src = s; a.pjobs[pi].dst = d; a.pjobs[pi].M = M; a.pjobs[pi].K = K;
      a.pjobs[pi].tilesX = M / 32; a.pjobs[pi].blockStart = pbs;
      pbs += (K / 32) * (M / 32); ++pi;
    };
    addT(Wg_l,             WgT_l_T, 128, 128);
    addT(Wg_l + 128 * 128, WgB_l_T, 128, 128);
    addT(Wu_l,             Wu_l_T,  128, 128);
    addT(Wg_p,             WgT_p_T, 128, 128);
    addT(Wg_p + 128 * 128, WgB_p_T, 128, 128);
    addT(Wu_p,             Wu_p_T,  128, 128);
    addT(W1_p, W1_p_T, 128, 512);
    addT(W2_p, W2_p_T, 512, 128);
    addT(W1_l, W1_l_T, 128, 512);
    addT(W2_l, W2_l_T, 512, 128);
    a.nprep = pi;
    l1_kernel<<<dim3(a.nQkv + pbs), dim3(256), 0, stream>>>(a);
  }

  // ---- K2: fused per-stripe attention + tail ----
  {
    K2Args k;
    k.qkv_p = qkv_p; k.qkv_l = qkv_l;
    k.h_f[0] = h_p; k.h_f[1] = h_l;
    k.WgT[0] = WgT_p_T; k.WgT[1] = WgT_l_T;
    k.WgB[0] = WgB_p_T; k.WgB[1] = WgB_l_T;
    k.WuT[0] = Wu_p_T;  k.WuT[1] = Wu_l_T;
    k.bg[0] = bg_p; k.bg[1] = bg_l;
    k.bu[0] = bu_p; k.bu[1] = bu_l;
    k.lng[0] = ln_p_g; k.lng[1] = ln_l_g;
    k.lnb[0] = ln_p_b; k.lnb[1] = ln_l_b;
    k.W1T[0] = W1_p_T; k.W1T[1] = W1_l_T;
    k.W2T[0] = W2_p_T; k.W2T[1] = W2_l_T;
    k.b1[0] = b1_p; k.b1[1] = b1_l;
    k.b2[0] = b2_p; k.b2[1] = b2_l;
    k.out[0] = out; k.out[1] = out + (size_t)NPROT * DMODEL;
    k2_kernel<<<dim3(NLIG / TR + NPROT / TR), dim3(256), 0, stream>>>(k);
  }
}